// Round 7
// baseline (115.161 us; speedup 1.0000x reference)
//
#include <hip/hip_runtime.h>
#include <math.h>

#define F 8
#define C 4096
#define NOFF 28             // i<j factor pairs (diag G_ii is closed-form)
#define NPAIR 36            // i<=j pairs
#define EPSF 1e-8f

#define QCHUNK 64           // q per block
#define NCHUNK (C / QCHUNK) // 64
#define PBLK 256            // p per block, one per thread
#define NPB (C / PBLK)      // 16
#define NBLK (NPB * NCHUNK) // 1024 blocks = exactly 4/CU resident

#define NSB 128             // sred blocks: each owns 32 p
#define SOUT_N 88           // D[36]|T[8]|Q[8]|T0[8]|G[28]

// ws layout (all plain stores, no init needed):
//   part [NCHUNK][F][C]   row-sum partials (8 MB)
//   gpart[NBLK][NOFF]     per-block off-diag Gram partials (112 KB)
//   sout [NSB][SOUT_N]    per-sred-block partials (45 KB)
#define WS_PART (NCHUNK * F * C)
#define WS_GP   (NBLK * NOFF)

__device__ __forceinline__ float wave_reduce(float v) {
    #pragma unroll
    for (int off = 32; off > 0; off >>= 1) v += __shfl_down(v, off, 64);
    return v;
}

// One q-slot: a[8] live for only this slot (8 regs, not 32), feeding the
// 28-pair FMA cluster. abs folds into VOP3 source modifiers.
#define SLOT(COMP)                                                          \
    {                                                                       \
        float a[F];                                                         \
        _Pragma("unroll")                                                   \
        for (int f = 0; f < F; ++f) {                                       \
            a[f] = __builtin_fabsf(cur[f].COMP - xp[f]);                    \
            rs[f] += a[f];                                                  \
        }                                                                   \
        int k = 0;                                                          \
        _Pragma("unroll")                                                   \
        for (int i = 0; i < F; ++i) {                                       \
            _Pragma("unroll")                                               \
            for (int j = i + 1; j < F; ++j) {                               \
                g[k] = __builtin_fmaf(a[i], a[j], g[k]);                    \
                ++k;                                                        \
            }                                                               \
        }                                                                   \
    }

// Each lane owns one p; q values are wave-uniform VECTOR loads (opaque VGPR
// zero laundered into the address so we get global_load_dwordx4 with counted
// vmcnt waits, not out-of-order SMEM). KEY CHANGE vs rounds 2-6:
// __launch_bounds__(256, 4) raises the VGPR budget 64 -> 128. At 64 the
// live set (v[32]+a+g[28]+rs+xp ~= 108) could not be allocated, and the
// compiler re-issued the q-loads inside the pair loop - the serialized
// reloads were the ~70% stall that was invariant to the load path.
// Now the double-buffered prefetch (cur/nxt = 64 regs) is physically
// realizable and one iteration of compute hides the L1 broadcast latency.
__global__ __launch_bounds__(256, 4) void pair_kernel(const float* __restrict__ x,
                                                      float* __restrict__ part,
                                                      float* __restrict__ gpart) {
    __shared__ float red[4][NOFF];
    const int tid  = threadIdx.x;
    const int lane = tid & 63;
    const int wave = tid >> 6;
    const int pb   = blockIdx.x & (NPB - 1);
    const int qc   = blockIdx.x >> 4;                // NPB == 16
    const int p    = pb * PBLK + tid;

    int lzero;
    asm volatile("v_mov_b32 %0, 0" : "=v"(lzero));   // opaque 0 in a VGPR

    float xp[F];
    #pragma unroll
    for (int f = 0; f < F; ++f) xp[f] = x[f * C + p];

    float g[NOFF];
    #pragma unroll
    for (int k = 0; k < NOFF; ++k) g[k] = 0.0f;
    float rs[F];
    #pragma unroll
    for (int f = 0; f < F; ++f) rs[f] = 0.0f;

    const float4* xqb = (const float4*)x + qc * (QCHUNK / 4) + lzero;

    float4 cur[F];
    #pragma unroll
    for (int f = 0; f < F; ++f) cur[f] = xqb[f * (C / 4)];

    #pragma unroll 2
    for (int g4 = 0; g4 < QCHUNK / 4; ++g4) {
        // prefetch next octet (wraps on last iter; harmless reload)
        const int nidx = (g4 + 1) & (QCHUNK / 4 - 1);
        float4 nxt[F];
        #pragma unroll
        for (int f = 0; f < F; ++f) nxt[f] = xqb[f * (C / 4) + nidx];

        SLOT(x)
        SLOT(y)
        SLOT(z)
        SLOT(w)

        #pragma unroll
        for (int f = 0; f < F; ++f) cur[f] = nxt[f];
    }

    // row-sum partials: plain coalesced stores
    #pragma unroll
    for (int f = 0; f < F; ++f) part[(qc * F + f) * C + p] = rs[f];

    // per-BLOCK gram partials: wave reduce -> LDS -> 28 plain stores
    #pragma unroll
    for (int k = 0; k < NOFF; ++k) g[k] = wave_reduce(g[k]);
    if (lane == 0) {
        #pragma unroll
        for (int k = 0; k < NOFF; ++k) red[wave][k] = g[k];
    }
    __syncthreads();
    if (tid < NOFF)
        gpart[blockIdx.x * NOFF + tid] =
            red[0][tid] + red[1][tid] + red[2][tid] + red[3][tid];
}

// 128 blocks x 256 threads. Block b owns 32 p values. Threads: pi = tid&31,
// qg = tid>>5 -> each sums 8 q-chunks for its p; LDS combine -> full s_f(p);
// wave 0 forms D/T/Q/T0 and reduces. Tids [64,176) reduce this block's
// 8-row slice of the gram partials in parallel.
__global__ __launch_bounds__(256) void sred_kernel(const float* __restrict__ x,
                                                   const float* __restrict__ part,
                                                   const float* __restrict__ gpart,
                                                   float* __restrict__ sout) {
    __shared__ float sp[8][F][32];      // 8 KB
    __shared__ float gred[NOFF][4];
    const int tid = threadIdx.x;
    const int pi  = tid & 31;
    const int qg  = tid >> 5;
    const int b   = blockIdx.x;
    const int p   = b * 32 + pi;

    float acc[F];
    #pragma unroll
    for (int f = 0; f < F; ++f) acc[f] = 0.0f;
    #pragma unroll 4
    for (int qq = 0; qq < NCHUNK / 8; ++qq) {
        const int qc = qg * (NCHUNK / 8) + qq;
        #pragma unroll
        for (int f = 0; f < F; ++f) acc[f] += part[(qc * F + f) * C + p];
    }
    #pragma unroll
    for (int f = 0; f < F; ++f) sp[qg][f][pi] = acc[f];
    __syncthreads();

    // gram partial slice: 112 threads, 4-way parallel over this block's 8 rows
    if (tid >= 64 && tid < 64 + NOFF * 4) {
        const int idx = tid - 64, gk = idx >> 2, c = idx & 3;
        float s = 0.0f;
        #pragma unroll
        for (int i = 0; i < 2; ++i)
            s += gpart[(b * 8 + c + 4 * i) * NOFF + gk];
        gred[gk][c] = s;
    }

    if (tid < 64) {
        float vals[60];                 // D[36] | T[8] | Q[8] | T0[8]
        if (tid < 32) {
            float sv[F], xv[F];
            #pragma unroll
            for (int f = 0; f < F; ++f) {
                float s = 0.0f;
                #pragma unroll
                for (int g2 = 0; g2 < 8; ++g2) s += sp[g2][f][pi];
                sv[f] = s;
                xv[f] = x[f * C + p];
            }
            int k = 0;
            #pragma unroll
            for (int i = 0; i < F; ++i)
                #pragma unroll
                for (int j = i; j < F; ++j) { vals[k] = sv[i] * sv[j]; ++k; }
            #pragma unroll
            for (int f = 0; f < F; ++f) vals[36 + f] = sv[f];
            #pragma unroll
            for (int f = 0; f < F; ++f) vals[44 + f] = xv[f] * xv[f];
            #pragma unroll
            for (int f = 0; f < F; ++f) vals[52 + f] = xv[f];
        } else {
            #pragma unroll
            for (int k = 0; k < 60; ++k) vals[k] = 0.0f;
        }
        #pragma unroll
        for (int k = 0; k < 60; ++k) vals[k] = wave_reduce(vals[k]);
        if (tid == 0) {
            #pragma unroll
            for (int k = 0; k < 60; ++k) sout[b * SOUT_N + k] = vals[k];
        }
    }
    __syncthreads();
    if (tid < NOFF)
        sout[b * SOUT_N + 60 + tid] =
            gred[tid][0] + gred[tid][1] + gred[tid][2] + gred[tid][3];
}

__global__ __launch_bounds__(256) void finish_kernel(const float* __restrict__ sout,
                                                     float* __restrict__ out) {
    // A: D[0,36) | T[36,44) | Q[44,52) | T0[52,60) | G_offdiag[60,88)
    __shared__ float fA[SOUT_N][2];
    __shared__ float A[SOUT_N];
    const int tid = threadIdx.x;
    if (tid < SOUT_N * 2) {
        const int col = tid >> 1, h = tid & 1;
        float s = 0.0f;
        #pragma unroll 16
        for (int i = 0; i < NSB / 2; ++i)
            s += sout[(h * (NSB / 2) + i) * SOUT_N + col];
        fA[col][h] = s;
    }
    __syncthreads();
    if (tid < SOUT_N) A[tid] = fA[tid][0] + fA[tid][1];
    __syncthreads();
    if (tid == 0) {
        const float invC  = 1.0f / (float)C;   // 2^-12, exact
        const float invC2 = invC * invC;       // 2^-24, exact
        float dcov[NPAIR], diag[F];
        int k = 0, ko = 0;
        for (int i = 0; i < F; ++i)
            for (int j = i; j < F; ++j) {
                float G;
                if (i == j) {
                    // closed form: sum_pq (x_p - x_q)^2 = 2C*sum(x^2) - 2*(sum x)^2
                    G = 2.0f * (float)C * A[44 + i] - 2.0f * A[52 + i] * A[52 + i];
                } else {
                    G = A[60 + ko]; ++ko;
                }
                // S_ij = G/C^2 - 2 D/C^3 + T_i T_j / C^4
                const float S = G * invC2 - 2.0f * A[k] * invC2 * invC
                              + (A[36 + i] * invC2) * (A[36 + j] * invC2);
                const float dc = __builtin_amdgcn_sqrtf(fmaxf(S, 0.0f) + EPSF);
                dcov[k] = dc;
                if (i == j) diag[i] = dc;
                ++k;
            }
        float cor = 0.0f;
        k = 0;
        for (int i = 0; i < F; ++i)
            for (int j = i; j < F; ++j) {
                if (j > i)
                    cor += dcov[k] * __builtin_amdgcn_rcpf(
                               __builtin_amdgcn_sqrtf(diag[i] * diag[j] + EPSF));
                ++k;
            }
        out[0] = cor;
    }
}

extern "C" void kernel_launch(void* const* d_in, const int* in_sizes, int n_in,
                              void* d_out, int out_size, void* d_ws, size_t ws_size,
                              hipStream_t stream) {
    const float* x = (const float*)d_in[0];
    float* part  = (float*)d_ws;
    float* gpart = part + WS_PART;
    float* sout  = gpart + WS_GP;
    float* out   = (float*)d_out;

    hipLaunchKernelGGL(pair_kernel,   dim3(NBLK), dim3(256), 0, stream, x, part, gpart);
    hipLaunchKernelGGL(sred_kernel,   dim3(NSB),  dim3(256), 0, stream, x, part, gpart, sout);
    hipLaunchKernelGGL(finish_kernel, dim3(1),    dim3(256), 0, stream, sout, out);
}

// Round 8
// 91.540 us; speedup vs baseline: 1.2580x; 1.2580x over previous
//
#include <hip/hip_runtime.h>
#include <math.h>

#define F 8
#define C 4096
#define NOFF 28             // i<j factor pairs (diag G_ii is closed-form)
#define NPAIR 36            // i<=j pairs
#define EPSF 1e-8f

#define QCHUNK 64           // q per block
#define NCHUNK (C / QCHUNK) // 64
#define PBLK 256            // p per block, one per thread
#define NPB (C / PBLK)      // 16
#define NBLK (NPB * NCHUNK) // 1024 blocks = 4/CU

#define NSB 128             // sred blocks: each owns 32 p
#define SOUT_N 88           // D[36]|T[8]|Q[8]|T0[8]|G[28]

// ws layout (all plain stores, no init needed):
//   xT   [C][F]           transposed x (128 KB)
//   part [NCHUNK][F][C]   row-sum partials (8 MB)
//   gpart[NBLK][NOFF]     per-block off-diag Gram partials (112 KB)
//   sout [NSB][SOUT_N]    per-sred-block partials (45 KB)
#define WS_XT   (C * F)
#define WS_PART (NCHUNK * F * C)
#define WS_GP   (NBLK * NOFF)

__device__ __forceinline__ float wave_reduce(float v) {
    #pragma unroll
    for (int off = 32; off > 0; off >>= 1) v += __shfl_down(v, off, 64);
    return v;
}

// x[8][4096] -> xT[4096][8]: coalesced reads per factor, 32 B/lane
// contiguous float4x2 writes. Makes a 4-q octet of all 8 factors a single
// 128 B contiguous span for pair_kernel's scalar loads.
__global__ __launch_bounds__(256) void trans_kernel(const float* __restrict__ x,
                                                    float* __restrict__ xT) {
    const int p = blockIdx.x * 256 + threadIdx.x;
    float v[F];
    #pragma unroll
    for (int f = 0; f < F; ++f) v[f] = x[f * C + p];
    float4 lo = make_float4(v[0], v[1], v[2], v[3]);
    float4 hi = make_float4(v[4], v[5], v[6], v[7]);
    ((float4*)xT)[p * 2]     = lo;
    ((float4*)xT)[p * 2 + 1] = hi;
}

// Each lane owns one p. A 4-q group of all factors = 128 contiguous bytes of
// xT at a BLOCK-UNIFORM address -> the compiler merges it into 2x
// s_load_dwordx16 into SGPRs: one lgkmcnt wait per 144-VALU compute block
// (vs one per 36 when q was 8 scattered row loads), and the q data costs
// ZERO VGPRs. Live VGPR set: a[8]+xp[8]+g[28]+rs[8] ~= 55 < 64, so the
// allocator's 8-wave heuristic fits with no spills and no reloads (R7's
// spill signature: WRITE_SIZE 51.8 MB vs 8.5 MB algorithmic).
__global__ __launch_bounds__(256) void pair_kernel(const float* __restrict__ x,
                                                   const float* __restrict__ xT,
                                                   float* __restrict__ part,
                                                   float* __restrict__ gpart) {
    __shared__ float red[4][NOFF];
    const int tid  = threadIdx.x;
    const int lane = tid & 63;
    const int wave = tid >> 6;
    const int pb   = blockIdx.x & (NPB - 1);
    const int qc   = blockIdx.x >> 4;                // NPB == 16
    const int p    = pb * PBLK + tid;

    float xp[F];
    #pragma unroll
    for (int f = 0; f < F; ++f) xp[f] = x[f * C + p];

    float g[NOFF];
    #pragma unroll
    for (int k = 0; k < NOFF; ++k) g[k] = 0.0f;
    float rs[F];
    #pragma unroll
    for (int f = 0; f < F; ++f) rs[f] = 0.0f;

    const float4* xt4 = (const float4*)xT;           // row q = 2 float4s
    const int qbase = qc * QCHUNK;

    #pragma unroll 2
    for (int qi = 0; qi < QCHUNK; qi += 4) {
        // 8 consecutive float4s = rows qbase+qi .. +3, all factors (128 B)
        float4 qv[8];
        #pragma unroll
        for (int t = 0; t < 8; ++t) qv[t] = xt4[(qbase + qi) * 2 + t];

        #pragma unroll
        for (int s = 0; s < 4; ++s) {
            const float4 lo4 = qv[2 * s], hi4 = qv[2 * s + 1];
            float a[F];
            a[0] = lo4.x - xp[0];
            a[1] = lo4.y - xp[1];
            a[2] = lo4.z - xp[2];
            a[3] = lo4.w - xp[3];
            a[4] = hi4.x - xp[4];
            a[5] = hi4.y - xp[5];
            a[6] = hi4.z - xp[6];
            a[7] = hi4.w - xp[7];
            #pragma unroll
            for (int f = 0; f < F; ++f) rs[f] += __builtin_fabsf(a[f]);
            int k = 0;
            #pragma unroll
            for (int i = 0; i < F; ++i) {
                #pragma unroll
                for (int j = i + 1; j < F; ++j) {
                    // |a_i|,|a_j| fold into VOP3 source modifiers
                    g[k] = __builtin_fmaf(__builtin_fabsf(a[i]),
                                          __builtin_fabsf(a[j]), g[k]);
                    ++k;
                }
            }
        }
    }

    // row-sum partials: plain coalesced stores
    #pragma unroll
    for (int f = 0; f < F; ++f) part[(qc * F + f) * C + p] = rs[f];

    // per-BLOCK gram partials: wave reduce -> LDS -> 28 plain stores
    #pragma unroll
    for (int k = 0; k < NOFF; ++k) g[k] = wave_reduce(g[k]);
    if (lane == 0) {
        #pragma unroll
        for (int k = 0; k < NOFF; ++k) red[wave][k] = g[k];
    }
    __syncthreads();
    if (tid < NOFF)
        gpart[blockIdx.x * NOFF + tid] =
            red[0][tid] + red[1][tid] + red[2][tid] + red[3][tid];
}

// 128 blocks x 256 threads. Block b owns 32 p values. Threads: pi = tid&31,
// qg = tid>>5 -> each sums 8 q-chunks for its p; LDS combine -> full s_f(p);
// wave 0 forms D/T/Q/T0 and reduces. Tids [64,176) reduce this block's
// 8-row slice of the gram partials in parallel.
__global__ __launch_bounds__(256) void sred_kernel(const float* __restrict__ x,
                                                   const float* __restrict__ part,
                                                   const float* __restrict__ gpart,
                                                   float* __restrict__ sout) {
    __shared__ float sp[8][F][32];      // 8 KB
    __shared__ float gred[NOFF][4];
    const int tid = threadIdx.x;
    const int pi  = tid & 31;
    const int qg  = tid >> 5;
    const int b   = blockIdx.x;
    const int p   = b * 32 + pi;

    float acc[F];
    #pragma unroll
    for (int f = 0; f < F; ++f) acc[f] = 0.0f;
    #pragma unroll 4
    for (int qq = 0; qq < NCHUNK / 8; ++qq) {
        const int qc = qg * (NCHUNK / 8) + qq;
        #pragma unroll
        for (int f = 0; f < F; ++f) acc[f] += part[(qc * F + f) * C + p];
    }
    #pragma unroll
    for (int f = 0; f < F; ++f) sp[qg][f][pi] = acc[f];
    __syncthreads();

    // gram partial slice: 112 threads, 4-way parallel over this block's 8 rows
    if (tid >= 64 && tid < 64 + NOFF * 4) {
        const int idx = tid - 64, gk = idx >> 2, c = idx & 3;
        float s = 0.0f;
        #pragma unroll
        for (int i = 0; i < 2; ++i)
            s += gpart[(b * 8 + c + 4 * i) * NOFF + gk];
        gred[gk][c] = s;
    }

    if (tid < 64) {
        float vals[60];                 // D[36] | T[8] | Q[8] | T0[8]
        if (tid < 32) {
            float sv[F], xv[F];
            #pragma unroll
            for (int f = 0; f < F; ++f) {
                float s = 0.0f;
                #pragma unroll
                for (int g2 = 0; g2 < 8; ++g2) s += sp[g2][f][pi];
                sv[f] = s;
                xv[f] = x[f * C + p];
            }
            int k = 0;
            #pragma unroll
            for (int i = 0; i < F; ++i)
                #pragma unroll
                for (int j = i; j < F; ++j) { vals[k] = sv[i] * sv[j]; ++k; }
            #pragma unroll
            for (int f = 0; f < F; ++f) vals[36 + f] = sv[f];
            #pragma unroll
            for (int f = 0; f < F; ++f) vals[44 + f] = xv[f] * xv[f];
            #pragma unroll
            for (int f = 0; f < F; ++f) vals[52 + f] = xv[f];
        } else {
            #pragma unroll
            for (int k = 0; k < 60; ++k) vals[k] = 0.0f;
        }
        #pragma unroll
        for (int k = 0; k < 60; ++k) vals[k] = wave_reduce(vals[k]);
        if (tid == 0) {
            #pragma unroll
            for (int k = 0; k < 60; ++k) sout[b * SOUT_N + k] = vals[k];
        }
    }
    __syncthreads();
    if (tid < NOFF)
        sout[b * SOUT_N + 60 + tid] =
            gred[tid][0] + gred[tid][1] + gred[tid][2] + gred[tid][3];
}

__global__ __launch_bounds__(256) void finish_kernel(const float* __restrict__ sout,
                                                     float* __restrict__ out) {
    // A: D[0,36) | T[36,44) | Q[44,52) | T0[52,60) | G_offdiag[60,88)
    __shared__ float fA[SOUT_N][2];
    __shared__ float A[SOUT_N];
    const int tid = threadIdx.x;
    if (tid < SOUT_N * 2) {
        const int col = tid >> 1, h = tid & 1;
        float s = 0.0f;
        #pragma unroll 16
        for (int i = 0; i < NSB / 2; ++i)
            s += sout[(h * (NSB / 2) + i) * SOUT_N + col];
        fA[col][h] = s;
    }
    __syncthreads();
    if (tid < SOUT_N) A[tid] = fA[tid][0] + fA[tid][1];
    __syncthreads();
    if (tid == 0) {
        const float invC  = 1.0f / (float)C;   // 2^-12, exact
        const float invC2 = invC * invC;       // 2^-24, exact
        float dcov[NPAIR], diag[F];
        int k = 0, ko = 0;
        for (int i = 0; i < F; ++i)
            for (int j = i; j < F; ++j) {
                float G;
                if (i == j) {
                    // closed form: sum_pq (x_p - x_q)^2 = 2C*sum(x^2) - 2*(sum x)^2
                    G = 2.0f * (float)C * A[44 + i] - 2.0f * A[52 + i] * A[52 + i];
                } else {
                    G = A[60 + ko]; ++ko;
                }
                // S_ij = G/C^2 - 2 D/C^3 + T_i T_j / C^4
                const float S = G * invC2 - 2.0f * A[k] * invC2 * invC
                              + (A[36 + i] * invC2) * (A[36 + j] * invC2);
                const float dc = __builtin_amdgcn_sqrtf(fmaxf(S, 0.0f) + EPSF);
                dcov[k] = dc;
                if (i == j) diag[i] = dc;
                ++k;
            }
        float cor = 0.0f;
        k = 0;
        for (int i = 0; i < F; ++i)
            for (int j = i; j < F; ++j) {
                if (j > i)
                    cor += dcov[k] * __builtin_amdgcn_rcpf(
                               __builtin_amdgcn_sqrtf(diag[i] * diag[j] + EPSF));
                ++k;
            }
        out[0] = cor;
    }
}

extern "C" void kernel_launch(void* const* d_in, const int* in_sizes, int n_in,
                              void* d_out, int out_size, void* d_ws, size_t ws_size,
                              hipStream_t stream) {
    const float* x = (const float*)d_in[0];
    float* xT    = (float*)d_ws;
    float* part  = xT + WS_XT;
    float* gpart = part + WS_PART;
    float* sout  = gpart + WS_GP;
    float* out   = (float*)d_out;

    hipLaunchKernelGGL(trans_kernel,  dim3(NPB),  dim3(256), 0, stream, x, xT);
    hipLaunchKernelGGL(pair_kernel,   dim3(NBLK), dim3(256), 0, stream, x, xT, part, gpart);
    hipLaunchKernelGGL(sred_kernel,   dim3(NSB),  dim3(256), 0, stream, x, part, gpart, sout);
    hipLaunchKernelGGL(finish_kernel, dim3(1),    dim3(256), 0, stream, sout, out);
}